// Round 8
// baseline (342.173 us; speedup 1.0000x reference)
//
#include <hip/hip_runtime.h>

typedef __bf16 bf16_t;
typedef __bf16 bf16x2 __attribute__((ext_vector_type(2)));
typedef __bf16 bf16x4 __attribute__((ext_vector_type(4)));
typedef __bf16 bf16x8 __attribute__((ext_vector_type(8)));
typedef float f32x4 __attribute__((ext_vector_type(4)));

#define S_LEN 2048
#define BSZ 4
#define NHEAD 16
#define HDIM 64
#define RDIM 1024
#define QKV_N 3072
#define NTOK 8192

// ---------------- async global->LDS (16B per lane, linear dest) ----------------
__device__ static inline void gload_lds16(const void* g, void* l) {
    __builtin_amdgcn_global_load_lds(
        (const __attribute__((address_space(1))) void*)(unsigned long long)g,
        (__attribute__((address_space(3))) void*)(unsigned long long)l,
        16, 0, 0);
}

// ---------------- LayerNorm: fp32 [8192][1024] -> bf16 xn ----------------
__global__ __launch_bounds__(256) void ln_kernel(const float* __restrict__ x,
                                                 const float* __restrict__ lw,
                                                 const float* __restrict__ lb,
                                                 bf16_t* __restrict__ xn) {
    int row = blockIdx.x;
    int tid = threadIdx.x;
    const float4* xr = (const float4*)(x + (size_t)row * RDIM);
    float4 v = xr[tid];
    float s  = v.x + v.y + v.z + v.w;
    float ss = v.x*v.x + v.y*v.y + v.z*v.z + v.w*v.w;
#pragma unroll
    for (int off = 1; off < 64; off <<= 1) {
        s  += __shfl_xor(s, off, 64);
        ss += __shfl_xor(ss, off, 64);
    }
    __shared__ float red[8];
    int wid = tid >> 6, lane = tid & 63;
    if (lane == 0) { red[wid] = s; red[wid + 4] = ss; }
    __syncthreads();
    float S  = red[0] + red[1] + red[2] + red[3];
    float SS = red[4] + red[5] + red[6] + red[7];
    float mu  = S * (1.f / RDIM);
    float var = SS * (1.f / RDIM) - mu * mu;
    float rsig = rsqrtf(var + 1e-5f);
    float4 wv = ((const float4*)lw)[tid];
    float4 bv = ((const float4*)lb)[tid];
    bf16x4 o;
    o[0] = (bf16_t)((v.x - mu) * rsig * wv.x + bv.x);
    o[1] = (bf16_t)((v.y - mu) * rsig * wv.y + bv.y);
    o[2] = (bf16_t)((v.z - mu) * rsig * wv.z + bv.z);
    o[3] = (bf16_t)((v.w - mu) * rsig * wv.w + bv.w);
    *(bf16x4*)(xn + (size_t)row * RDIM + tid * 4) = o;
}

// ---------------- fp32 -> bf16 convert (weights) ----------------
__global__ __launch_bounds__(256) void cvt_kernel(const float* __restrict__ src,
                                                  bf16_t* __restrict__ dst, int n4) {
    int i = blockIdx.x * 256 + threadIdx.x;
    if (i < n4) {
        float4 v = ((const float4*)src)[i];
        bf16x4 o;
        o[0] = (bf16_t)v.x; o[1] = (bf16_t)v.y; o[2] = (bf16_t)v.z; o[3] = (bf16_t)v.w;
        ((bf16x4*)dst)[i] = o;
    }
}

// ---------------- GEMM C = A @ B^T  (A [M][1024] bf16, B [N][1024] bf16) -------
// MODE 0: qkv-split epilogue -> Qb [tok][1024], kT [b,h,s,64], vT [b,h,64,s]
// MODE 1: C = acc + X (fp32 residual), fp32 out, stride ldc
template <int MODE>
__global__ __launch_bounds__(256) void gemm_bt_kernel(const bf16_t* __restrict__ A,
                                                      const bf16_t* __restrict__ Bm,
                                                      bf16_t* __restrict__ Qb,
                                                      bf16_t* __restrict__ kTd,
                                                      bf16_t* __restrict__ vTd,
                                                      const float* __restrict__ X,
                                                      float* __restrict__ Cf,
                                                      int ldc) {
    const int K = 1024;
    __shared__ bf16_t As[128 * 32];
    __shared__ bf16_t Bs[128 * 32];
    int tid = threadIdx.x;
    int lane = tid & 63, wid = tid >> 6;
    int l15 = lane & 15, lg = lane >> 4;
    int wm = wid >> 1, wn = wid & 1;
    int row0 = blockIdx.y * 128;
    int col0 = blockIdx.x * 128;

    int sr = tid >> 2;
    int sc = (tid & 3) * 8;
    const bf16_t* aSrc = A + (size_t)(row0 + sr) * K + sc;
    const bf16_t* bSrc = Bm + (size_t)(col0 + sr) * K + sc;
    bf16_t* aDst = As + tid * 8;
    bf16_t* bDst = Bs + tid * 8;

    f32x4 acc[4][4] = {};
    for (int kt = 0; kt < K; kt += 32) {
        gload_lds16(aSrc + kt, aDst);
        gload_lds16(aSrc + kt + (size_t)64 * K, aDst + 2048);
        gload_lds16(bSrc + kt, bDst);
        gload_lds16(bSrc + kt + (size_t)64 * K, bDst + 2048);
        __syncthreads();
        bf16x8 a[4], b[4];
#pragma unroll
        for (int m = 0; m < 4; m++)
            a[m] = *(const bf16x8*)(As + (wm * 64 + m * 16 + l15) * 32 + lg * 8);
#pragma unroll
        for (int n = 0; n < 4; n++)
            b[n] = *(const bf16x8*)(Bs + (wn * 64 + n * 16 + l15) * 32 + lg * 8);
#pragma unroll
        for (int m = 0; m < 4; m++)
#pragma unroll
            for (int n = 0; n < 4; n++)
                acc[m][n] = __builtin_amdgcn_mfma_f32_16x16x32_bf16(a[m], b[n], acc[m][n], 0, 0, 0);
        __syncthreads();
    }

    int crow = row0 + wm * 64 + lg * 4;
    int ccol = col0 + wn * 64 + l15;
#pragma unroll
    for (int n = 0; n < 4; n++) {
        int cc = ccol + n * 16;
        if (MODE == 0) {
            int h = cc / 192;          // head
            int r = cc - h * 192;      // 0..63 q, 64..127 k, 128..191 v (span-uniform)
#pragma unroll
            for (int m = 0; m < 4; m++) {
#pragma unroll
                for (int rv = 0; rv < 4; rv++) {
                    int rr = crow + m * 16 + rv;   // token = s*4 + b
                    bf16_t val = (bf16_t)acc[m][n][rv];
                    int bb = rr & 3, s = rr >> 2;
                    if (r < 64) {
                        Qb[(size_t)rr * RDIM + h * 64 + r] = val;
                    } else if (r < 128) {
                        kTd[((size_t)(bb * NHEAD + h) * S_LEN + s) * 64 + (r - 64)] = val;
                    } else {
                        vTd[((size_t)(bb * NHEAD + h) * 64 + (r - 128)) * S_LEN + s] = val;
                    }
                }
            }
        } else {
#pragma unroll
            for (int m = 0; m < 4; m++) {
#pragma unroll
                for (int rv = 0; rv < 4; rv++) {
                    int rr = crow + m * 16 + rv;
                    size_t idx = (size_t)rr * ldc + cc;
                    Cf[idx] = acc[m][n][rv] + X[idx];
                }
            }
        }
    }
}

// ---------------- Flash attention v2 (all-DMA staging, 40KB LDS) ----------
// grid (32 qblocks, 4 batch, 16 heads), 256 threads = 4 waves, 16 queries/wave.
// K LDS [key][64], V LDS [d][64 keys]: both row-stride 128B, 16B chunks
//   XOR-swizzled by row&7, staged by gload_lds with pre-swizzled global source.
// P LDS per-wave [16][64], 16B-slot XOR-swizzled by q&7.
__global__ __launch_bounds__(256) void attn_kernel(const bf16_t* __restrict__ Qb,
                                                   const bf16_t* __restrict__ kT,
                                                   const bf16_t* __restrict__ vT,
                                                   bf16_t* __restrict__ aout) {
    __shared__ __align__(16) bf16_t Kb[2][4096];
    __shared__ __align__(16) bf16_t Vb[2][4096];
    __shared__ __align__(16) bf16_t Ps[4][1024];
    int tid = threadIdx.x;
    int lane = tid & 63, wid = tid >> 6;
    int l15 = lane & 15, lg = lane >> 4;
    int b = blockIdx.y, h = blockIdx.z;
    int sq = blockIdx.x * 64 + wid * 16 + l15;

    const float c2 = 0.04508422002778011f;  // (1/32) * log2(e)

    const bf16_t* qbase = Qb + (size_t)(sq * 4 + b) * RDIM + h * 64;
    bf16x8 qf0 = *(const bf16x8*)(qbase + lg * 8);
    bf16x8 qf1 = *(const bf16x8*)(qbase + 32 + lg * 8);

    // ---- staging decode: dest (row=tid>>3, slot=tid&7); source chunk = slot^(row&7)
    int srow = tid >> 3, sslot = tid & 7;
    int sx = sslot ^ (srow & 7);
    const bf16_t* kS = kT + ((size_t)(b * NHEAD + h) * S_LEN + srow) * 64 + sx * 8;
    const bf16_t* vS = vT + ((size_t)(b * NHEAD + h) * 64 + srow) * S_LEN + sx * 8;

    int sw = l15 & 7;
    int koA = (lg ^ sw) * 8;
    int koC = ((lg + 4) ^ sw) * 8;

    float mh = -3e38f, lrun = 0.f;
    f32x4 o[4] = {};

    // ---- prologue: stage tile 0 into buf 0 ----
    gload_lds16(kS, &Kb[0][tid * 8]);
    gload_lds16(kS + 32 * 64, &Kb[0][2048 + tid * 8]);
    gload_lds16(vS, &Vb[0][tid * 8]);
    gload_lds16(vS + (size_t)32 * S_LEN, &Vb[0][2048 + tid * 8]);
    __syncthreads();

    int cur = 0;
    for (int t = 0; t < S_LEN / 64; t++) {
        // ---- stage tile t+1 into buf cur^1 ----
        if (t + 1 < S_LEN / 64) {
            const bf16_t* k2 = kS + (size_t)(t + 1) * 64 * 64;
            const bf16_t* v2 = vS + (t + 1) * 64;
            gload_lds16(k2, &Kb[cur ^ 1][tid * 8]);
            gload_lds16(k2 + 32 * 64, &Kb[cur ^ 1][2048 + tid * 8]);
            gload_lds16(v2, &Vb[cur ^ 1][tid * 8]);
            gload_lds16(v2 + (size_t)32 * S_LEN, &Vb[cur ^ 1][2048 + tid * 8]);
        }

        // ---- QK^T (swapped): sc4[kb] = K-rows . Q-rows ----
        const bf16_t* kbase = &Kb[cur][l15 * 64];
        bf16x8 kfA[4], kfC[4];
#pragma unroll
        for (int kb = 0; kb < 4; kb++) {
            kfA[kb] = *(const bf16x8*)(kbase + kb * 1024 + koA);
            kfC[kb] = *(const bf16x8*)(kbase + kb * 1024 + koC);
        }
        f32x4 sc4[4];
        __builtin_amdgcn_s_setprio(1);
#pragma unroll
        for (int kb = 0; kb < 4; kb++) {
            f32x4 z = {0.f, 0.f, 0.f, 0.f};
            z = __builtin_amdgcn_mfma_f32_16x16x32_bf16(kfA[kb], qf0, z, 0, 0, 0);
            z = __builtin_amdgcn_mfma_f32_16x16x32_bf16(kfC[kb], qf1, z, 0, 0, 0);
            sc4[kb] = z;
        }
        __builtin_amdgcn_s_setprio(0);

        // ---- online softmax (exp2 form; m tracked in log2 units; P <= 1) ----
        float tmax = sc4[0][0];
#pragma unroll
        for (int kb = 0; kb < 4; kb++)
#pragma unroll
            for (int r = 0; r < 4; r++) tmax = fmaxf(tmax, sc4[kb][r]);
        tmax = fmaxf(tmax, __shfl_xor(tmax, 16, 64));
        tmax = fmaxf(tmax, __shfl_xor(tmax, 32, 64));
        float mn = fmaxf(mh, tmax * c2);
        float corr = __builtin_amdgcn_exp2f(mh - mn);
        float lsum = 0.f;
#pragma unroll
        for (int kb = 0; kb < 4; kb++) {
            float p0 = __builtin_amdgcn_exp2f(fmaf(sc4[kb][0], c2, -mn));
            float p1 = __builtin_amdgcn_exp2f(fmaf(sc4[kb][1], c2, -mn));
            float p2 = __builtin_amdgcn_exp2f(fmaf(sc4[kb][2], c2, -mn));
            float p3 = __builtin_amdgcn_exp2f(fmaf(sc4[kb][3], c2, -mn));
            lsum += (p0 + p1) + (p2 + p3);
            bf16x4 pw;
            pw[0] = (bf16_t)p0; pw[1] = (bf16_t)p1; pw[2] = (bf16_t)p2; pw[3] = (bf16_t)p3;
            int j = (kb * 2 + (lg >> 1)) ^ sw;   // swizzled 16B slot
            *(bf16x4*)(&Ps[wid][l15 * 64 + j * 8 + (lg & 1) * 4]) = pw;
        }
        lsum += __shfl_xor(lsum, 16, 64);
        lsum += __shfl_xor(lsum, 32, 64);
        lrun = lrun * corr + lsum;
        mh = mn;
#pragma unroll
        for (int dc = 0; dc < 4; dc++) {
            o[dc][0] *= corr; o[dc][1] *= corr; o[dc][2] *= corr; o[dc][3] *= corr;
        }

        // ---- PV: O^T[d][q] += V^T[d][k] * P[q][k] ----
#pragma unroll
        for (int kc = 0; kc < 2; kc++) {
            int cslot = (kc * 4 + lg) ^ sw;
            bf16x8 pf = *(const bf16x8*)(&Ps[wid][l15 * 64 + cslot * 8]);
            __builtin_amdgcn_s_setprio(1);
#pragma unroll
            for (int dc = 0; dc < 4; dc++) {
                bf16x8 vf = *(const bf16x8*)(&Vb[cur][(dc * 16 + l15) * 64 + cslot * 8]);
                o[dc] = __builtin_amdgcn_mfma_f32_16x16x32_bf16(vf, pf, o[dc], 0, 0, 0);
            }
            __builtin_amdgcn_s_setprio(0);
        }

        __syncthreads();
        cur ^= 1;
    }

    float linv = 1.f / lrun;
    bf16_t* ob = aout + (size_t)(sq * 4 + b) * RDIM + h * 64 + lg * 4;
#pragma unroll
    for (int dc = 0; dc < 4; dc++) {
        bf16x4 ov;
        ov[0] = (bf16_t)(o[dc][0] * linv);
        ov[1] = (bf16_t)(o[dc][1] * linv);
        ov[2] = (bf16_t)(o[dc][2] * linv);
        ov[3] = (bf16_t)(o[dc][3] * linv);
        *(bf16x4*)(ob + dc * 16) = ov;
    }
}

// ---------------- host launch ----------------
extern "C" void kernel_launch(void* const* d_in, const int* in_sizes, int n_in,
                              void* d_out, int out_size, void* d_ws, size_t ws_size,
                              hipStream_t stream) {
    (void)in_sizes; (void)n_in; (void)out_size; (void)ws_size;
    const float* x     = (const float*)d_in[0];
    const float* w_qkv = (const float*)d_in[1];
    const float* w_out = (const float*)d_in[2];
    const float* ln_w  = (const float*)d_in[3];
    const float* ln_b  = (const float*)d_in[4];
    float* out = (float*)d_out;
    char* ws = (char*)d_ws;

    bf16_t* xn      = (bf16_t*)(ws);                 // 16,777,216 B
    bf16_t* wqkv_bf = (bf16_t*)(ws + 16777216);      //  6,291,456 B
    bf16_t* wout_bf = (bf16_t*)(ws + 23068672);      //  2,097,152 B
    bf16_t* Qb      = (bf16_t*)(ws + 25165824);      // 16,777,216 B
    bf16_t* kT      = (bf16_t*)(ws + 41943040);      // 16,777,216 B
    bf16_t* vT      = (bf16_t*)(ws + 58720256);      // 16,777,216 B (end 75,497,472)
    bf16_t* attn    = xn;  // xn dead after QKV GEMM

    ln_kernel<<<NTOK, 256, 0, stream>>>(x, ln_w, ln_b, xn);
    cvt_kernel<<<3072, 256, 0, stream>>>(w_qkv, wqkv_bf, (QKV_N * RDIM) / 4);
    cvt_kernel<<<1024, 256, 0, stream>>>(w_out, wout_bf, (RDIM * RDIM) / 4);

    gemm_bt_kernel<0><<<dim3(QKV_N / 128, NTOK / 128), 256, 0, stream>>>(
        xn, wqkv_bf, Qb, kT, vT, nullptr, nullptr, 0);

    attn_kernel<<<dim3(S_LEN / 64, BSZ, NHEAD), 256, 0, stream>>>(Qb, kT, vT, attn);

    gemm_bt_kernel<1><<<dim3(RDIM / 128, NTOK / 128), 256, 0, stream>>>(
        attn, wout_bf, nullptr, nullptr, nullptr, x, out, RDIM);
}